// Round 8
// baseline (363.542 us; speedup 1.0000x reference)
//
#include <hip/hip_runtime.h>
#include <hip/hip_bf16.h>

typedef float f32x4 __attribute__((ext_vector_type(4)));
typedef short s16x8 __attribute__((ext_vector_type(8)));

#define DEVI __device__ __forceinline__

DEVI unsigned short f2bf(float f) {
    return __builtin_bit_cast(unsigned short, __float2bfloat16(f));
}

// Geometry: B=4, C=128, H=W=360, r=9, h=w=40, T=1600 tokens, R2=81 features.
// token t = hh*40+ww, feature k = ch*9+cw, pixel (ch*40+hh, cw*40+ww).
// MFMA mapping (verified R1-R7): D col = lane&15 = B-operand row,
// D row = (lane>>4)*4 + reg = A-operand row; A/B frag: row = lane&15,
// k = (lane>>4)*8 + elem.

// ---------------------------------------------------------------------------
// Kernel 0 (fused prep):
//  blocks 0..63 : Wconv f32 -> bf16
//  blocks 64..99: EAT[j][i] = sum_p WA'[p][i] WB'[p][j]; WCAT[l][q] = Wc[q][l]/bc[q].
__global__ __launch_bounds__(256) void k_prep(
    const float* __restrict__ W, const float* __restrict__ Wa,
    const float* __restrict__ ba, const float* __restrict__ Wb,
    const float* __restrict__ bb, const float* __restrict__ Wc,
    const float* __restrict__ bc, unsigned short* __restrict__ Wbf,
    float* __restrict__ EAT, float* __restrict__ WCAT)
{
    const int tid = threadIdx.x, bid = blockIdx.x;
    if (bid < 64) {
        const int i = bid * 256 + tid;
        Wbf[i] = f2bf(W[i]);
        return;
    }
    const int out = (bid - 64) * 256 + tid; // 0..9215
    const int row = out / 96, col = out % 96;
    float ea = 0.f;
    if (row <= 81 && col <= 81) {
        for (int p = 0; p < 81; ++p) {
            const float wa = (col < 81) ? Wa[p * 81 + col] : ba[p];
            const float wb = (row < 81) ? Wb[p * 81 + row] : bb[p];
            ea += wa * wb;
        }
    }
    EAT[out] = ea;
    float wc = 0.f;
    if (col < 81) {
        if (row < 81) wc = Wc[col * 81 + row];
        else if (row == 81) wc = bc[col];
    }
    WCAT[out] = wc;
}

// ---------------------------------------------------------------------------
// conv helpers (uniform barriers inside).
DEVI void conv_issue(const float* xb, int H0, int w0, int tid, float4 (&va)[5][4])
{
#pragma unroll
    for (int ii = 0; ii < 5; ++ii) {
        const int i = tid + ii * 256;
        const int cq = i / 40, nq = i % 40;
        const int hh = nq / 10, sub = nq % 10;
        const float* p = xb + (size_t)(cq * 4) * 129600 + (size_t)(H0 + hh) * 360 + w0 + sub * 4;
        va[ii][0] = *reinterpret_cast<const float4*>(p);
        va[ii][1] = *reinterpret_cast<const float4*>(p + 129600);
        va[ii][2] = *reinterpret_cast<const float4*>(p + 2 * 129600);
        va[ii][3] = *reinterpret_cast<const float4*>(p + 3 * 129600);
    }
}

DEVI void conv_stage(const float4 (&va)[5][4], unsigned short* Xs, int tid)
{
#pragma unroll
    for (int ii = 0; ii < 5; ++ii) {
        const int i = tid + ii * 256;
        const int cq = i / 40, nq = i % 40;
        const int hh = nq / 10, sub = nq % 10;
        const int n0 = hh * 40 + sub * 4;
        const int cs = (cq ^ ((((n0 >> 2)) & 7) << 1)) * 4;
        const float4 v0 = va[ii][0], v1 = va[ii][1], v2 = va[ii][2], v3 = va[ii][3];
        ushort4 w0v = { f2bf(v0.x), f2bf(v1.x), f2bf(v2.x), f2bf(v3.x) };
        ushort4 w1v = { f2bf(v0.y), f2bf(v1.y), f2bf(v2.y), f2bf(v3.y) };
        ushort4 w2v = { f2bf(v0.z), f2bf(v1.z), f2bf(v2.z), f2bf(v3.z) };
        ushort4 w3v = { f2bf(v0.w), f2bf(v1.w), f2bf(v2.w), f2bf(v3.w) };
        *reinterpret_cast<ushort4*>(&Xs[(n0 + 0) * 136 + cs]) = w0v;
        *reinterpret_cast<ushort4*>(&Xs[(n0 + 1) * 136 + cs]) = w1v;
        *reinterpret_cast<ushort4*>(&Xs[(n0 + 2) * 136 + cs]) = w2v;
        *reinterpret_cast<ushort4*>(&Xs[(n0 + 3) * 136 + cs]) = w3v;
    }
}

// MFMA + bounce epilogue + coalesced store (enters after Xs published;
// leaves with Xs free for reuse after final barrier).
DEVI void conv_compute_store(unsigned short* Xs, const unsigned short* __restrict__ Wbf,
                             const float* __restrict__ bcv, unsigned short* dstb, int tid)
{
    const int lane = tid & 63, wid = tid >> 6;
    const int wm = wid >> 1, wn = wid & 1;
    const int lr = lane & 15, lg = lane >> 4;

    f32x4 acc[5][4] = {};
#pragma unroll
    for (int kk = 0; kk < 4; ++kk) {
        s16x8 xa[5], wb[4];
#pragma unroll
        for (int at = 0; at < 5; ++at) {
            const int n = wm * 80 + at * 16 + lr;
            const int cqs = ((kk * 8 + lg * 2) ^ (((n >> 2) & 7) << 1)) * 4;
            xa[at] = *reinterpret_cast<const s16x8*>(&Xs[n * 136 + cqs]);
        }
#pragma unroll
        for (int bt = 0; bt < 4; ++bt)
            wb[bt] = *reinterpret_cast<const s16x8*>(
                Wbf + (wn * 64 + bt * 16 + lr) * 128 + kk * 32 + lg * 8);
#pragma unroll
        for (int at = 0; at < 5; ++at)
#pragma unroll
            for (int bt = 0; bt < 4; ++bt)
                acc[at][bt] = __builtin_amdgcn_mfma_f32_16x16x32_bf16(xa[at], wb[bt], acc[at][bt], 0, 0, 0);
    }
    __syncthreads();
#pragma unroll
    for (int bt = 0; bt < 4; ++bt) {
        const int o = wn * 64 + bt * 16 + lr;
        const float bias = bcv[o];
#pragma unroll
        for (int at = 0; at < 5; ++at) {
            const int n0 = wm * 80 + at * 16 + lg * 4;
            ushort4 hv = { f2bf(acc[at][bt][0] + bias), f2bf(acc[at][bt][1] + bias),
                           f2bf(acc[at][bt][2] + bias), f2bf(acc[at][bt][3] + bias) };
            *reinterpret_cast<ushort4*>(&Xs[o * 168 + n0]) = hv;
        }
    }
    __syncthreads();
#pragma unroll
    for (int j = 0; j < 10; ++j) {
        const int item = tid + j * 256;      // 2560 = 128 o x 20 segs
        const int o = item / 20, s2 = item % 20;
        *reinterpret_cast<s16x8*>(dstb + (size_t)o * 129600 + s2 * 8) =
            *reinterpret_cast<const s16x8*>(&Xs[o * 168 + s2 * 8]);
    }
    __syncthreads(); // Xs free
}

// ---------------------------------------------------------------------------
// Kernel 1: 1x1 conv GEMM, pipelined: 2 rb-tiles/block, next tile's global
// loads issued right after the Xs-publish barrier (T14 issue-early).
// Grid 1620. XR: bf16 [bo=512][81][1600]
__global__ __launch_bounds__(256, 2) void k_conv(
    const float* __restrict__ x, const unsigned short* __restrict__ Wbf,
    const float* __restrict__ bcv, unsigned short* __restrict__ XR)
{
    __shared__ __align__(16) unsigned short Xs[160 * 136]; // 43.5 KB
    const int tid = threadIdx.x;
    int bid = blockIdx.x;
    const int rb2 = bid % 5; bid /= 5;
    const int cw = bid % 9;  bid /= 9;
    const int ch = bid % 9;  const int b = bid / 9;
    const int w0 = cw * 40;
    const int kfeat = ch * 9 + cw;
    const int rb0 = rb2 * 2;
    const int H0a = ch * 40 + rb0 * 4;

    const float* xb = x + (size_t)b * 128 * 129600;
    unsigned short* dst0 = XR + (size_t)(b * 128) * 129600 + (size_t)kfeat * 1600;

    float4 va[5][4], vb[5][4];
    conv_issue(xb, H0a, w0, tid, va);
    conv_stage(va, Xs, tid);           // waits va
    __syncthreads();                   // Xs published
    conv_issue(xb, H0a + 4, w0, tid, vb); // prefetch tile 1 (covered by MFMA+epi)
    conv_compute_store(Xs, Wbf, bcv, dst0 + rb0 * 160, tid);

    conv_stage(vb, Xs, tid);           // waits vb (mostly complete)
    __syncthreads();
    conv_compute_store(Xs, Wbf, bcv, dst0 + (rb0 + 1) * 160, tid);
}

// ---------------------------------------------------------------------------
// Kernel 2: partial Gram per (half,bo): G2 = R R^T over 800 tokens (96-pad),
// row 81 = ones so col 81 = partial s.  Grid 1024.
__global__ __launch_bounds__(256) void k_gram(
    const unsigned short* __restrict__ XR, float* __restrict__ G2)
{
    __shared__ __align__(16) unsigned short Rs[96 * 168];
    const int tid = threadIdx.x;
    const int half = blockIdx.x & 1, bo = blockIdx.x >> 1;
    for (int i = 81 * 168 + tid; i < 96 * 168; i += 256)
        Rs[i] = (i < 82 * 168) ? (unsigned short)0x3F80 : (unsigned short)0;
    const unsigned short* Rg = XR + (size_t)bo * 129600;
    const int lane = tid & 63, wid = tid >> 6;
    const int wm = wid >> 1, wn = wid & 1;
    const int lr = lane & 15, lg = lane >> 4;
    f32x4 acc[3][3] = {};
    for (int it = 0; it < 5; ++it) {
        const int t0 = half * 800 + it * 160;
        __syncthreads();
        for (int i = tid; i < 81 * 20; i += 256) {
            const int r = i / 20, g = i % 20;
            *reinterpret_cast<s16x8*>(&Rs[r * 168 + g * 8]) =
                *reinterpret_cast<const s16x8*>(Rg + (size_t)r * 1600 + t0 + g * 8);
        }
        __syncthreads();
#pragma unroll
        for (int kk = 0; kk < 5; ++kk) {
            const int koff = kk * 32 + lg * 8;
            s16x8 af[3], bfr[3];
#pragma unroll
            for (int mt = 0; mt < 3; ++mt)
                af[mt] = *reinterpret_cast<const s16x8*>(&Rs[(wm * 48 + mt * 16 + lr) * 168 + koff]);
#pragma unroll
            for (int nt = 0; nt < 3; ++nt)
                bfr[nt] = *reinterpret_cast<const s16x8*>(&Rs[(wn * 48 + nt * 16 + lr) * 168 + koff]);
#pragma unroll
            for (int mt = 0; mt < 3; ++mt)
#pragma unroll
                for (int nt = 0; nt < 3; ++nt)
                    acc[mt][nt] = __builtin_amdgcn_mfma_f32_16x16x32_bf16(af[mt], bfr[nt], acc[mt][nt], 0, 0, 0);
        }
    }
    float* Gb = G2 + (size_t)(half * 512 + bo) * 9216;
#pragma unroll
    for (int mt = 0; mt < 3; ++mt)
#pragma unroll
        for (int nt = 0; nt < 3; ++nt)
#pragma unroll
            for (int rg = 0; rg < 4; ++rg) {
                const int row = wm * 48 + mt * 16 + lg * 4 + rg;
                const int col = wn * 48 + nt * 16 + lr;
                Gb[row * 96 + col] = acc[mt][nt][rg];
            }
}

// ---------------------------------------------------------------------------
// Kernel 3: per bo: OUT = EA * Ghat * WCA^T / 9. NT[q][k] = OUT[k][q].
__global__ __launch_bounds__(256) void k_small(
    const float* __restrict__ G2, const float* __restrict__ EAT,
    const float* __restrict__ WCAT, unsigned short* __restrict__ NT)
{
    __shared__ float Gs[96 * 98];
    __shared__ float Us[96 * 98];
    const int tid = threadIdx.x;
    const int bo = blockIdx.x;
    const int ty = tid >> 4, tx = tid & 15;
    const int r0 = ty * 6, q0 = tx * 6;

    const float* Gg0 = G2 + (size_t)bo * 9216;
    const float* Gg1 = G2 + (size_t)(512 + bo) * 9216;
    for (int i = tid; i < 96 * 96; i += 256) {
        const int r = i / 96, c = i % 96;
        Gs[r * 98 + c] = Gg0[i] + Gg1[i];
    }
    __syncthreads();

    {
        float acc[6][6] = {};
        for (int l = 0; l <= 81; ++l) {
            float gv[6], wv[6];
#pragma unroll
            for (int a = 0; a < 6; ++a) gv[a] = Gs[l * 98 + r0 + a];
#pragma unroll
            for (int b2 = 0; b2 < 6; ++b2) wv[b2] = WCAT[l * 96 + q0 + b2];
#pragma unroll
            for (int a = 0; a < 6; ++a)
#pragma unroll
                for (int b2 = 0; b2 < 6; ++b2)
                    acc[a][b2] += gv[a] * wv[b2];
        }
#pragma unroll
        for (int a = 0; a < 6; ++a)
#pragma unroll
            for (int b2 = 0; b2 < 6; ++b2)
                Us[(r0 + a) * 98 + q0 + b2] = acc[a][b2];
    }
    __syncthreads();

    float acc[6][6] = {};
    for (int j = 0; j <= 81; ++j) {
        float ev[6], uv[6];
#pragma unroll
        for (int a = 0; a < 6; ++a) ev[a] = EAT[j * 96 + r0 + a];
#pragma unroll
        for (int b2 = 0; b2 < 6; ++b2) uv[b2] = Us[j * 98 + q0 + b2];
#pragma unroll
        for (int a = 0; a < 6; ++a)
#pragma unroll
            for (int b2 = 0; b2 < 6; ++b2)
                acc[a][b2] += ev[a] * uv[b2];
    }
    unsigned short* NTb = NT + (size_t)bo * 9216;
#pragma unroll
    for (int b2 = 0; b2 < 6; ++b2)
#pragma unroll
        for (int a = 0; a < 6; ++a)
            NTb[(q0 + b2) * 96 + (r0 + a)] = f2bf(acc[a][b2] * (1.f / 9.f));
}

// ---------------------------------------------------------------------------
// apply helpers.
DEVI void apply_issue(const unsigned short* Rg, int t0, int tid, s16x8 (&pf)[2][4])
{
    {
        const int kq = tid / 20, g = tid % 20;   // kq <= 12: regular
        const unsigned short* src = Rg + (size_t)(4 * kq) * 1600 + t0 + g * 8;
        pf[0][0] = *reinterpret_cast<const s16x8*>(src);
        pf[0][1] = *reinterpret_cast<const s16x8*>(src + 1600);
        pf[0][2] = *reinterpret_cast<const s16x8*>(src + 3200);
        pf[0][3] = *reinterpret_cast<const s16x8*>(src + 4800);
    }
    if (tid < 164) {
        const int item = tid + 256;
        const int kq = item / 20, g = item % 20;
        if (kq < 20) {
            const unsigned short* src = Rg + (size_t)(4 * kq) * 1600 + t0 + g * 8;
            pf[1][0] = *reinterpret_cast<const s16x8*>(src);
            pf[1][1] = *reinterpret_cast<const s16x8*>(src + 1600);
            pf[1][2] = *reinterpret_cast<const s16x8*>(src + 3200);
            pf[1][3] = *reinterpret_cast<const s16x8*>(src + 4800);
        } else {
            pf[1][0] = *reinterpret_cast<const s16x8*>(
                Rg + (size_t)80 * 1600 + t0 + g * 8);
        }
    }
}

DEVI void apply_stage(int tid, const s16x8 (&pf)[2][4], unsigned short* Xs)
{
    {
        const int kq = tid / 20, g = tid % 20;
        const int colb = (((kq >> 1) ^ (g & 7)) << 3) + ((kq & 1) << 2);
#pragma unroll
        for (int e = 0; e < 8; ++e) {
            const int t = g * 8 + e;
            ushort4 wv = { (unsigned short)pf[0][0][e], (unsigned short)pf[0][1][e],
                           (unsigned short)pf[0][2][e], (unsigned short)pf[0][3][e] };
            *reinterpret_cast<ushort4*>(&Xs[t * 128 + colb]) = wv;
        }
    }
    if (tid < 164) {
        const int item = tid + 256;
        const int kq = item / 20, g = item % 20;
        if (kq < 20) {
            const int colb = (((kq >> 1) ^ (g & 7)) << 3) + ((kq & 1) << 2);
#pragma unroll
            for (int e = 0; e < 8; ++e) {
                const int t = g * 8 + e;
                ushort4 wv = { (unsigned short)pf[1][0][e], (unsigned short)pf[1][1][e],
                               (unsigned short)pf[1][2][e], (unsigned short)pf[1][3][e] };
                *reinterpret_cast<ushort4*>(&Xs[t * 128 + colb]) = wv;
            }
        } else {
            const int colb = (10 ^ (g & 7)) << 3;
#pragma unroll
            for (int e = 0; e < 8; ++e) {
                const int t = g * 8 + e;
                ushort4 wv = { (unsigned short)pf[1][0][e], (unsigned short)0x3F80, 0, 0 };
                *reinterpret_cast<ushort4*>(&Xs[t * 128 + colb]) = wv;
            }
        }
    }
}

// ---------------------------------------------------------------------------
// Kernel 4: y[t][q] = sum_k x~[t][k] N[k][q] + m[q]. Pipelined: 5 t-tiles per
// block (grid 1024), NT frags loaded once, next tile's loads issued after the
// Xs-publish barrier. col8-XOR swizzled [t][128] LDS; f32x4 stores.
__global__ __launch_bounds__(256) void k_apply(
    const unsigned short* __restrict__ XR, const unsigned short* __restrict__ NT,
    float* __restrict__ out)
{
    __shared__ __align__(16) unsigned short Xs[160 * 128]; // 40 KB
    const int tid = threadIdx.x;
    const int half = blockIdx.x & 1, bo = blockIdx.x >> 1;
    const int t00 = half * 800;
    // init zeros for logical cols 84..95 (col8 = 10 upper half, col8 = 11)
    for (int i = tid; i < 320; i += 256) {
        const int t = i >> 1, h = i & 1;
        const int s = (t >> 3) & 7;
        const ushort4 z = { 0, 0, 0, 0 };
        if (h == 0) {
            *reinterpret_cast<ushort4*>(&Xs[t * 128 + ((10 ^ s) << 3) + 4]) = z;
        } else {
            *reinterpret_cast<ushort4*>(&Xs[t * 128 + ((11 ^ s) << 3)]) = z;
            *reinterpret_cast<ushort4*>(&Xs[t * 128 + ((11 ^ s) << 3) + 4]) = z;
        }
    }
    const int lane = tid & 63, wid = tid >> 6;
    const int wm = wid >> 1, wn = wid & 1;  // wm: t-half (80), wn: q-half (48)
    const int lr = lane & 15, lg = lane >> 4;

    const unsigned short* NTb = NT + (size_t)bo * 9216;
    s16x8 nb[3][3];
#pragma unroll
    for (int qt = 0; qt < 3; ++qt)
#pragma unroll
        for (int kk = 0; kk < 3; ++kk)
            nb[qt][kk] = *reinterpret_cast<const s16x8*>(
                NTb + (wn * 48 + qt * 16 + lr) * 96 + kk * 32 + lg * 8);

    const unsigned short* Rg = XR + (size_t)bo * 129600;
    float* ob = out + (size_t)bo * 129600;

    s16x8 pf[2][2][4];
    apply_issue(Rg, t00, tid, pf[0]);

#pragma unroll
    for (int it = 0; it < 5; ++it) {
        const int t0 = t00 + it * 160;
        apply_stage(tid, pf[it & 1], Xs);   // waits this tile's loads
        __syncthreads();                    // Xs published
        if (it < 4)
            apply_issue(Rg, t0 + 160, tid, pf[(it & 1) ^ 1]); // prefetch
        f32x4 acc[5][3] = {};
#pragma unroll
        for (int kk = 0; kk < 3; ++kk) {
            s16x8 xa[5];
#pragma unroll
            for (int at = 0; at < 5; ++at) {
                const int t = wm * 80 + at * 16 + lr;
                const int s = (t >> 3) & 7;
                xa[at] = *reinterpret_cast<const s16x8*>(
                    &Xs[t * 128 + (((kk * 4 + lg) ^ s) << 3)]);
            }
#pragma unroll
            for (int at = 0; at < 5; ++at)
#pragma unroll
                for (int qt = 0; qt < 3; ++qt)
                    acc[at][qt] = __builtin_amdgcn_mfma_f32_16x16x32_bf16(xa[at], nb[qt][kk], acc[at][qt], 0, 0, 0);
        }
#pragma unroll
        for (int qt = 0; qt < 3; ++qt) {
            const int q = wn * 48 + qt * 16 + lr;
            if (q < 81) {
                const int chq = q / 9, cwq = q % 9;
                float* oq = ob + (size_t)chq * 40 * 360 + cwq * 40;
#pragma unroll
                for (int at = 0; at < 5; ++at) {
                    const int tt = t0 + wm * 80 + at * 16 + lg * 4;
                    const int hh = tt / 40, ww = tt % 40;
                    *reinterpret_cast<f32x4*>(&oq[hh * 360 + ww]) = acc[at][qt];
                }
            }
        }
        __syncthreads();                    // Xs free for next stage
    }
}

// ---------------------------------------------------------------------------
extern "C" void kernel_launch(void* const* d_in, const int* in_sizes, int n_in,
                              void* d_out, int out_size, void* d_ws, size_t ws_size,
                              hipStream_t stream)
{
    (void)in_sizes; (void)n_in; (void)out_size; (void)ws_size;
    const float* x   = (const float*)d_in[0];
    const float* Wcv = (const float*)d_in[1];
    const float* bcv = (const float*)d_in[2];
    const float* Wa  = (const float*)d_in[3];
    const float* ba  = (const float*)d_in[4];
    const float* Wb  = (const float*)d_in[5];
    const float* bbv = (const float*)d_in[6];
    const float* Wc  = (const float*)d_in[7];
    const float* bc2 = (const float*)d_in[8];
    float* out = (float*)d_out;

    // ws: XR 132,710,400 | G2 37,748,736 | NT 9,437,184 | Wbf 32,768
    //   | EAT 36,864 | WCAT 36,864
    char* w = (char*)d_ws;
    unsigned short* XR = (unsigned short*)w;
    float* G2 = (float*)(w + 132710400ull);
    unsigned short* NT = (unsigned short*)(w + 170459136ull);
    unsigned short* Wbf = (unsigned short*)(w + 179896320ull);
    float* EAT  = (float*)(w + 179929088ull);
    float* WCAT = (float*)(w + 179965952ull);

    k_prep <<<100,  256, 0, stream>>>(Wcv, Wa, ba, Wb, bbv, Wc, bc2, Wbf, EAT, WCAT);
    k_conv <<<1620, 256, 0, stream>>>(x, Wbf, bcv, XR);
    k_gram <<<1024, 256, 0, stream>>>(XR, G2);
    k_small<<<512,  256, 0, stream>>>(G2, EAT, WCAT, NT);
    k_apply<<<1024, 256, 0, stream>>>(XR, NT, out);
}

// Round 9
// 362.137 us; speedup vs baseline: 1.0039x; 1.0039x over previous
//
#include <hip/hip_runtime.h>
#include <hip/hip_bf16.h>

typedef float f32x4 __attribute__((ext_vector_type(4)));
typedef short s16x8 __attribute__((ext_vector_type(8)));

#define DEVI __device__ __forceinline__

DEVI unsigned short f2bf(float f) {
    return __builtin_bit_cast(unsigned short, __float2bfloat16(f));
}

// Geometry: B=4, C=128, H=W=360, r=9, h=w=40, T=1600 tokens, R2=81 features.
// token t = hh*40+ww, feature k = ch*9+cw, pixel (ch*40+hh, cw*40+ww).
// MFMA mapping (verified R1-R8): D col = lane&15 = B-operand row,
// D row = (lane>>4)*4 + reg = A-operand row; A/B frag: row = lane&15,
// k = (lane>>4)*8 + elem.

// ---------------------------------------------------------------------------
// Kernel 0 (fused prep):
//  blocks 0..63 : Wconv f32 -> bf16
//  blocks 64..99: EAT[j][i] = sum_p WA'[p][i] WB'[p][j]; WCAT[l][q] = Wc[q][l]/bc[q].
__global__ __launch_bounds__(256) void k_prep(
    const float* __restrict__ W, const float* __restrict__ Wa,
    const float* __restrict__ ba, const float* __restrict__ Wb,
    const float* __restrict__ bb, const float* __restrict__ Wc,
    const float* __restrict__ bc, unsigned short* __restrict__ Wbf,
    float* __restrict__ EAT, float* __restrict__ WCAT)
{
    const int tid = threadIdx.x, bid = blockIdx.x;
    if (bid < 64) {
        const int i = bid * 256 + tid;
        Wbf[i] = f2bf(W[i]);
        return;
    }
    const int out = (bid - 64) * 256 + tid; // 0..9215
    const int row = out / 96, col = out % 96;
    float ea = 0.f;
    if (row <= 81 && col <= 81) {
        for (int p = 0; p < 81; ++p) {
            const float wa = (col < 81) ? Wa[p * 81 + col] : ba[p];
            const float wb = (row < 81) ? Wb[p * 81 + row] : bb[p];
            ea += wa * wb;
        }
    }
    EAT[out] = ea;
    float wc = 0.f;
    if (col < 81) {
        if (row < 81) wc = Wc[col * 81 + row];
        else if (row == 81) wc = bc[col];
    }
    WCAT[out] = wc;
}

// ---------------------------------------------------------------------------
// Kernel 1: 1x1 conv GEMM (R7 structure, grid 3240). LDS now [160 n][128 c]
// with col8-XOR swizzle (c8' = (c>>3) ^ ((n>>3)&7)) -> 40 KB = 4 blocks/CU.
// Epilogue bounce [o][160] with o-XOR on col bit-3, then coalesced store.
// XR: bf16 [bo=512][81][1600]
__global__ __launch_bounds__(256, 4) void k_conv(
    const float* __restrict__ x, const unsigned short* __restrict__ Wbf,
    const float* __restrict__ bcv, unsigned short* __restrict__ XR)
{
    __shared__ __align__(16) unsigned short Xs[160 * 128]; // 40960 B exactly
    const int tid = threadIdx.x;
    int bid = blockIdx.x;
    const int rb = bid % 10; bid /= 10;
    const int cw = bid % 9;  bid /= 9;
    const int ch = bid % 9;  const int b = bid / 9;
    const int H0 = ch * 40 + rb * 4, w0 = cw * 40;
    const int kfeat = ch * 9 + cw;
    const int t0 = rb * 160;

    // Load batch: 20 float4 per thread (1280 items = 32 cq x 40 nq).
    const float* xb = x + (size_t)b * 128 * 129600;
    float4 va[5][4];
#pragma unroll
    for (int ii = 0; ii < 5; ++ii) {
        const int i = tid + ii * 256;
        const int cq = i / 40, nq = i % 40;
        const int hh = nq / 10, sub = nq % 10;
        const float* p = xb + (size_t)(cq * 4) * 129600 + (size_t)(H0 + hh) * 360 + w0 + sub * 4;
        va[ii][0] = *reinterpret_cast<const float4*>(p);
        va[ii][1] = *reinterpret_cast<const float4*>(p + 129600);
        va[ii][2] = *reinterpret_cast<const float4*>(p + 2 * 129600);
        va[ii][3] = *reinterpret_cast<const float4*>(p + 3 * 129600);
    }
    // Stage with col8-XOR swizzle; swz const per item (n0..n0+3 same octet).
#pragma unroll
    for (int ii = 0; ii < 5; ++ii) {
        const int i = tid + ii * 256;
        const int cq = i / 40, nq = i % 40;
        const int hh = nq / 10, sub = nq % 10;
        const int n0 = hh * 40 + sub * 4;
        const int swz = (n0 >> 3) & 7;
        const int colb = (((cq >> 1) ^ swz) << 3) + ((cq & 1) << 2);
        const float4 v0 = va[ii][0], v1 = va[ii][1], v2 = va[ii][2], v3 = va[ii][3];
        ushort4 w0v = { f2bf(v0.x), f2bf(v1.x), f2bf(v2.x), f2bf(v3.x) };
        ushort4 w1v = { f2bf(v0.y), f2bf(v1.y), f2bf(v2.y), f2bf(v3.y) };
        ushort4 w2v = { f2bf(v0.z), f2bf(v1.z), f2bf(v2.z), f2bf(v3.z) };
        ushort4 w3v = { f2bf(v0.w), f2bf(v1.w), f2bf(v2.w), f2bf(v3.w) };
        *reinterpret_cast<ushort4*>(&Xs[(n0 + 0) * 128 + colb]) = w0v;
        *reinterpret_cast<ushort4*>(&Xs[(n0 + 1) * 128 + colb]) = w1v;
        *reinterpret_cast<ushort4*>(&Xs[(n0 + 2) * 128 + colb]) = w2v;
        *reinterpret_cast<ushort4*>(&Xs[(n0 + 3) * 128 + colb]) = w3v;
    }
    __syncthreads();

    const int lane = tid & 63, wid = tid >> 6;
    const int wm = wid >> 1, wn = wid & 1;  // wm: t-half (80), wn: o-half (64)
    const int lr = lane & 15, lg = lane >> 4;

    f32x4 acc[5][4] = {};
#pragma unroll
    for (int kk = 0; kk < 4; ++kk) {
        s16x8 xa[5], wb[4];
#pragma unroll
        for (int at = 0; at < 5; ++at) {
            const int n = wm * 80 + at * 16 + lr;
            const int col8 = (kk * 4 + lg) ^ ((n >> 3) & 7);
            xa[at] = *reinterpret_cast<const s16x8*>(&Xs[n * 128 + (col8 << 3)]);
        }
#pragma unroll
        for (int bt = 0; bt < 4; ++bt)
            wb[bt] = *reinterpret_cast<const s16x8*>(
                Wbf + (wn * 64 + bt * 16 + lr) * 128 + kk * 32 + lg * 8);
#pragma unroll
        for (int at = 0; at < 5; ++at)
#pragma unroll
            for (int bt = 0; bt < 4; ++bt)
                acc[at][bt] = __builtin_amdgcn_mfma_f32_16x16x32_bf16(xa[at], wb[bt], acc[at][bt], 0, 0, 0);
    }
    // Epilogue bounce: acc -> LDS [o][160] (o-XOR bit-3: 2-way banks).
    __syncthreads();
#pragma unroll
    for (int bt = 0; bt < 4; ++bt) {
        const int o = wn * 64 + bt * 16 + lr;
        const float bias = bcv[o];
        const int oswz = ((o >> 1) & 1) << 3;
#pragma unroll
        for (int at = 0; at < 5; ++at) {
            const int n0 = (wm * 80 + at * 16 + lg * 4) ^ oswz;
            ushort4 hv = { f2bf(acc[at][bt][0] + bias), f2bf(acc[at][bt][1] + bias),
                           f2bf(acc[at][bt][2] + bias), f2bf(acc[at][bt][3] + bias) };
            *reinterpret_cast<ushort4*>(&Xs[o * 160 + n0]) = hv;
        }
    }
    __syncthreads();
    unsigned short* dstb = XR + (size_t)b * 128 * 129600 + (size_t)kfeat * 1600 + t0;
#pragma unroll
    for (int j = 0; j < 10; ++j) {
        const int item = tid + j * 256;      // 2560 = 128 o x 20 segs
        const int o = item / 20, s2 = item % 20;
        const int s2s = s2 ^ ((o >> 1) & 1);
        *reinterpret_cast<s16x8*>(dstb + (size_t)o * 129600 + s2 * 8) =
            *reinterpret_cast<const s16x8*>(&Xs[o * 160 + s2s * 8]);
    }
}

// ---------------------------------------------------------------------------
// Kernel 2: partial Gram per (half,bo): G2 = R R^T over 800 tokens (96-pad),
// row 81 = ones so col 81 = partial s.  Grid 1024.
__global__ __launch_bounds__(256) void k_gram(
    const unsigned short* __restrict__ XR, float* __restrict__ G2)
{
    __shared__ __align__(16) unsigned short Rs[96 * 168];
    const int tid = threadIdx.x;
    const int half = blockIdx.x & 1, bo = blockIdx.x >> 1;
    for (int i = 81 * 168 + tid; i < 96 * 168; i += 256)
        Rs[i] = (i < 82 * 168) ? (unsigned short)0x3F80 : (unsigned short)0;
    const unsigned short* Rg = XR + (size_t)bo * 129600;
    const int lane = tid & 63, wid = tid >> 6;
    const int wm = wid >> 1, wn = wid & 1;
    const int lr = lane & 15, lg = lane >> 4;
    f32x4 acc[3][3] = {};
    for (int it = 0; it < 5; ++it) {
        const int t0 = half * 800 + it * 160;
        __syncthreads();
        for (int i = tid; i < 81 * 20; i += 256) {
            const int r = i / 20, g = i % 20;
            *reinterpret_cast<s16x8*>(&Rs[r * 168 + g * 8]) =
                *reinterpret_cast<const s16x8*>(Rg + (size_t)r * 1600 + t0 + g * 8);
        }
        __syncthreads();
#pragma unroll
        for (int kk = 0; kk < 5; ++kk) {
            const int koff = kk * 32 + lg * 8;
            s16x8 af[3], bfr[3];
#pragma unroll
            for (int mt = 0; mt < 3; ++mt)
                af[mt] = *reinterpret_cast<const s16x8*>(&Rs[(wm * 48 + mt * 16 + lr) * 168 + koff]);
#pragma unroll
            for (int nt = 0; nt < 3; ++nt)
                bfr[nt] = *reinterpret_cast<const s16x8*>(&Rs[(wn * 48 + nt * 16 + lr) * 168 + koff]);
#pragma unroll
            for (int mt = 0; mt < 3; ++mt)
#pragma unroll
                for (int nt = 0; nt < 3; ++nt)
                    acc[mt][nt] = __builtin_amdgcn_mfma_f32_16x16x32_bf16(af[mt], bfr[nt], acc[mt][nt], 0, 0, 0);
        }
    }
    float* Gb = G2 + (size_t)(half * 512 + bo) * 9216;
#pragma unroll
    for (int mt = 0; mt < 3; ++mt)
#pragma unroll
        for (int nt = 0; nt < 3; ++nt)
#pragma unroll
            for (int rg = 0; rg < 4; ++rg) {
                const int row = wm * 48 + mt * 16 + lg * 4 + rg;
                const int col = wn * 48 + nt * 16 + lr;
                Gb[row * 96 + col] = acc[mt][nt][rg];
            }
}

// ---------------------------------------------------------------------------
// Kernel 3: per bo: OUT = EA * Ghat * WCA^T / 9. NT[q][k] = OUT[k][q].
__global__ __launch_bounds__(256) void k_small(
    const float* __restrict__ G2, const float* __restrict__ EAT,
    const float* __restrict__ WCAT, unsigned short* __restrict__ NT)
{
    __shared__ float Gs[96 * 98];
    __shared__ float Us[96 * 98];
    const int tid = threadIdx.x;
    const int bo = blockIdx.x;
    const int ty = tid >> 4, tx = tid & 15;
    const int r0 = ty * 6, q0 = tx * 6;

    const float* Gg0 = G2 + (size_t)bo * 9216;
    const float* Gg1 = G2 + (size_t)(512 + bo) * 9216;
    for (int i = tid; i < 96 * 96; i += 256) {
        const int r = i / 96, c = i % 96;
        Gs[r * 98 + c] = Gg0[i] + Gg1[i];
    }
    __syncthreads();

    {
        float acc[6][6] = {};
        for (int l = 0; l <= 81; ++l) {
            float gv[6], wv[6];
#pragma unroll
            for (int a = 0; a < 6; ++a) gv[a] = Gs[l * 98 + r0 + a];
#pragma unroll
            for (int b2 = 0; b2 < 6; ++b2) wv[b2] = WCAT[l * 96 + q0 + b2];
#pragma unroll
            for (int a = 0; a < 6; ++a)
#pragma unroll
                for (int b2 = 0; b2 < 6; ++b2)
                    acc[a][b2] += gv[a] * wv[b2];
        }
#pragma unroll
        for (int a = 0; a < 6; ++a)
#pragma unroll
            for (int b2 = 0; b2 < 6; ++b2)
                Us[(r0 + a) * 98 + q0 + b2] = acc[a][b2];
    }
    __syncthreads();

    float acc[6][6] = {};
    for (int j = 0; j <= 81; ++j) {
        float ev[6], uv[6];
#pragma unroll
        for (int a = 0; a < 6; ++a) ev[a] = EAT[j * 96 + r0 + a];
#pragma unroll
        for (int b2 = 0; b2 < 6; ++b2) uv[b2] = Us[j * 98 + q0 + b2];
#pragma unroll
        for (int a = 0; a < 6; ++a)
#pragma unroll
            for (int b2 = 0; b2 < 6; ++b2)
                acc[a][b2] += ev[a] * uv[b2];
    }
    unsigned short* NTb = NT + (size_t)bo * 9216;
#pragma unroll
    for (int b2 = 0; b2 < 6; ++b2)
#pragma unroll
        for (int a = 0; a < 6; ++a)
            NTb[(q0 + b2) * 96 + (r0 + a)] = f2bf(acc[a][b2] * (1.f / 9.f));
}

// ---------------------------------------------------------------------------
// Kernel 4: y[t][q] = sum_k x~[t][k] N[k][q] + m[q]. R7 structure (grid 2560),
// col8-XOR swizzled [t][128] LDS, register-transpose staging, f32x4 stores.
__global__ __launch_bounds__(256, 4) void k_apply(
    const unsigned short* __restrict__ XR, const unsigned short* __restrict__ NT,
    float* __restrict__ out)
{
    __shared__ __align__(16) unsigned short Xs[160 * 128]; // 40 KB
    const int tid = threadIdx.x;
    const int fifth = blockIdx.x % 5, bo = blockIdx.x / 5;
    // init zeros for logical cols 84..95 (col8 = 10 upper half, col8 = 11)
    for (int i = tid; i < 320; i += 256) {
        const int t = i >> 1, h = i & 1;
        const int s = (t >> 3) & 7;
        const ushort4 z = { 0, 0, 0, 0 };
        if (h == 0) {
            *reinterpret_cast<ushort4*>(&Xs[t * 128 + ((10 ^ s) << 3) + 4]) = z;
        } else {
            *reinterpret_cast<ushort4*>(&Xs[t * 128 + ((11 ^ s) << 3)]) = z;
            *reinterpret_cast<ushort4*>(&Xs[t * 128 + ((11 ^ s) << 3) + 4]) = z;
        }
    }
    const int lane = tid & 63, wid = tid >> 6;
    const int wm = wid >> 1, wn = wid & 1;  // wm: t-half (80), wn: q-half (48)
    const int lr = lane & 15, lg = lane >> 4;

    const unsigned short* NTb = NT + (size_t)bo * 9216;
    s16x8 nb[3][3];
#pragma unroll
    for (int qt = 0; qt < 3; ++qt)
#pragma unroll
        for (int kk = 0; kk < 3; ++kk)
            nb[qt][kk] = *reinterpret_cast<const s16x8*>(
                NTb + (wn * 48 + qt * 16 + lr) * 96 + kk * 32 + lg * 8);

    const unsigned short* Rg = XR + (size_t)bo * 129600;
    float* ob = out + (size_t)bo * 129600;

    for (int it = 0; it < 2; ++it) {
        const int t0 = fifth * 320 + it * 160;
        __syncthreads();
        for (int i = tid; i < 420; i += 256) {
            const int kq = i / 20, g = i % 20;
            if (kq < 20) {
                const unsigned short* src = Rg + (size_t)(4 * kq) * 1600 + t0 + g * 8;
                const s16x8 v0 = *reinterpret_cast<const s16x8*>(src);
                const s16x8 v1 = *reinterpret_cast<const s16x8*>(src + 1600);
                const s16x8 v2 = *reinterpret_cast<const s16x8*>(src + 3200);
                const s16x8 v3 = *reinterpret_cast<const s16x8*>(src + 4800);
                const int colb = (((kq >> 1) ^ (g & 7)) << 3) + ((kq & 1) << 2);
#pragma unroll
                for (int e = 0; e < 8; ++e) {
                    const int t = g * 8 + e;
                    ushort4 wv = { (unsigned short)v0[e], (unsigned short)v1[e],
                                   (unsigned short)v2[e], (unsigned short)v3[e] };
                    *reinterpret_cast<ushort4*>(&Xs[t * 128 + colb]) = wv;
                }
            } else {
                const s16x8 v = *reinterpret_cast<const s16x8*>(
                    Rg + (size_t)80 * 1600 + t0 + g * 8);
                const int colb = (10 ^ (g & 7)) << 3;
#pragma unroll
                for (int e = 0; e < 8; ++e) {
                    const int t = g * 8 + e;
                    ushort4 wv = { (unsigned short)v[e], (unsigned short)0x3F80, 0, 0 };
                    *reinterpret_cast<ushort4*>(&Xs[t * 128 + colb]) = wv;
                }
            }
        }
        __syncthreads();
        f32x4 acc[5][3] = {};
#pragma unroll
        for (int kk = 0; kk < 3; ++kk) {
            s16x8 xa[5];
#pragma unroll
            for (int at = 0; at < 5; ++at) {
                const int t = wm * 80 + at * 16 + lr;
                const int s = (t >> 3) & 7;
                xa[at] = *reinterpret_cast<const s16x8*>(
                    &Xs[t * 128 + (((kk * 4 + lg) ^ s) << 3)]);
            }
#pragma unroll
            for (int at = 0; at < 5; ++at)
#pragma unroll
                for (int qt = 0; qt < 3; ++qt)
                    acc[at][qt] = __builtin_amdgcn_mfma_f32_16x16x32_bf16(xa[at], nb[qt][kk], acc[at][qt], 0, 0, 0);
        }
#pragma unroll
        for (int qt = 0; qt < 3; ++qt) {
            const int q = wn * 48 + qt * 16 + lr;
            if (q < 81) {
                const int chq = q / 9, cwq = q % 9;
                float* oq = ob + (size_t)chq * 40 * 360 + cwq * 40;
#pragma unroll
                for (int at = 0; at < 5; ++at) {
                    const int tt = t0 + wm * 80 + at * 16 + lg * 4;
                    const int hh = tt / 40, ww = tt % 40;
                    *reinterpret_cast<f32x4*>(&oq[hh * 360 + ww]) = acc[at][qt];
                }
            }
        }
    }
}

// ---------------------------------------------------------------------------
extern "C" void kernel_launch(void* const* d_in, const int* in_sizes, int n_in,
                              void* d_out, int out_size, void* d_ws, size_t ws_size,
                              hipStream_t stream)
{
    (void)in_sizes; (void)n_in; (void)out_size; (void)ws_size;
    const float* x   = (const float*)d_in[0];
    const float* Wcv = (const float*)d_in[1];
    const float* bcv = (const float*)d_in[2];
    const float* Wa  = (const float*)d_in[3];
    const float* ba  = (const float*)d_in[4];
    const float* Wb  = (const float*)d_in[5];
    const float* bbv = (const float*)d_in[6];
    const float* Wc  = (const float*)d_in[7];
    const float* bc2 = (const float*)d_in[8];
    float* out = (float*)d_out;

    // ws: XR 132,710,400 | G2 37,748,736 | NT 9,437,184 | Wbf 32,768
    //   | EAT 36,864 | WCAT 36,864
    char* w = (char*)d_ws;
    unsigned short* XR = (unsigned short*)w;
    float* G2 = (float*)(w + 132710400ull);
    unsigned short* NT = (unsigned short*)(w + 170459136ull);
    unsigned short* Wbf = (unsigned short*)(w + 179896320ull);
    float* EAT  = (float*)(w + 179929088ull);
    float* WCAT = (float*)(w + 179965952ull);

    k_prep <<<100,  256, 0, stream>>>(Wcv, Wa, ba, Wb, bbv, Wc, bc2, Wbf, EAT, WCAT);
    k_conv <<<3240, 256, 0, stream>>>(x, Wbf, bcv, XR);
    k_gram <<<1024, 256, 0, stream>>>(XR, G2);
    k_small<<<512,  256, 0, stream>>>(G2, EAT, WCAT, NT);
    k_apply<<<2560, 256, 0, stream>>>(XR, NT, out);
}

// Round 10
// 331.903 us; speedup vs baseline: 1.0953x; 1.0911x over previous
//
#include <hip/hip_runtime.h>
#include <hip/hip_bf16.h>

typedef float f32x4 __attribute__((ext_vector_type(4)));
typedef short s16x8 __attribute__((ext_vector_type(8)));

#define DEVI __device__ __forceinline__

DEVI unsigned short f2bf(float f) {
    return __builtin_bit_cast(unsigned short, __float2bfloat16(f));
}

// Geometry: B=4, C=128, H=W=360, r=9, h=w=40, T=1600 tokens, R2=81 features.
// token t = hh*40+ww, feature k = ch*9+cw, pixel (ch*40+hh, cw*40+ww).
// MFMA mapping (verified R1-R9): D col = lane&15 = B-operand row,
// D row = (lane>>4)*4 + reg = A-operand row; A/B frag: row = lane&15,
// k = (lane>>4)*8 + elem.

// ---------------------------------------------------------------------------
// Kernel 0 (fused prep):
//  blocks 0..63 : Wconv f32 -> bf16
//  blocks 64..99: EAT[j][i] = sum_p WA'[p][i] WB'[p][j]; WCAT[l][q] = Wc[q][l]/bc[q].
__global__ __launch_bounds__(256) void k_prep(
    const float* __restrict__ W, const float* __restrict__ Wa,
    const float* __restrict__ ba, const float* __restrict__ Wb,
    const float* __restrict__ bb, const float* __restrict__ Wc,
    const float* __restrict__ bc, unsigned short* __restrict__ Wbf,
    float* __restrict__ EAT, float* __restrict__ WCAT)
{
    const int tid = threadIdx.x, bid = blockIdx.x;
    if (bid < 64) {
        const int i = bid * 256 + tid;
        Wbf[i] = f2bf(W[i]);
        return;
    }
    const int out = (bid - 64) * 256 + tid; // 0..9215
    const int row = out / 96, col = out % 96;
    float ea = 0.f;
    if (row <= 81 && col <= 81) {
        for (int p = 0; p < 81; ++p) {
            const float wa = (col < 81) ? Wa[p * 81 + col] : ba[p];
            const float wb = (row < 81) ? Wb[p * 81 + row] : bb[p];
            ea += wa * wb;
        }
    }
    EAT[out] = ea;
    float wc = 0.f;
    if (col < 81) {
        if (row < 81) wc = Wc[col * 81 + row];
        else if (row == 81) wc = bc[col];
    }
    WCAT[out] = wc;
}

// ---------------------------------------------------------------------------
// conv helpers (R7-verified bodies).
DEVI void conv_issue(const float* xb, int H0, int w0, int tid, float4 (&va)[5][4])
{
#pragma unroll
    for (int ii = 0; ii < 5; ++ii) {
        const int i = tid + ii * 256;
        const int cq = i / 40, nq = i % 40;
        const int hh = nq / 10, sub = nq % 10;
        const float* p = xb + (size_t)(cq * 4) * 129600 + (size_t)(H0 + hh) * 360 + w0 + sub * 4;
        va[ii][0] = *reinterpret_cast<const float4*>(p);
        va[ii][1] = *reinterpret_cast<const float4*>(p + 129600);
        va[ii][2] = *reinterpret_cast<const float4*>(p + 2 * 129600);
        va[ii][3] = *reinterpret_cast<const float4*>(p + 3 * 129600);
    }
}

DEVI void conv_stage(const float4 (&va)[5][4], unsigned short* Xs, int tid)
{
#pragma unroll
    for (int ii = 0; ii < 5; ++ii) {
        const int i = tid + ii * 256;
        const int cq = i / 40, nq = i % 40;
        const int hh = nq / 10, sub = nq % 10;
        const int n0 = hh * 40 + sub * 4;
        const int cs = (cq ^ ((((n0 >> 2)) & 7) << 1)) * 4;
        const float4 v0 = va[ii][0], v1 = va[ii][1], v2 = va[ii][2], v3 = va[ii][3];
        ushort4 w0v = { f2bf(v0.x), f2bf(v1.x), f2bf(v2.x), f2bf(v3.x) };
        ushort4 w1v = { f2bf(v0.y), f2bf(v1.y), f2bf(v2.y), f2bf(v3.y) };
        ushort4 w2v = { f2bf(v0.z), f2bf(v1.z), f2bf(v2.z), f2bf(v3.z) };
        ushort4 w3v = { f2bf(v0.w), f2bf(v1.w), f2bf(v2.w), f2bf(v3.w) };
        *reinterpret_cast<ushort4*>(&Xs[(n0 + 0) * 136 + cs]) = w0v;
        *reinterpret_cast<ushort4*>(&Xs[(n0 + 1) * 136 + cs]) = w1v;
        *reinterpret_cast<ushort4*>(&Xs[(n0 + 2) * 136 + cs]) = w2v;
        *reinterpret_cast<ushort4*>(&Xs[(n0 + 3) * 136 + cs]) = w3v;
    }
}

// MFMA + bounce epilogue + coalesced store; internal barriers; Xs free on exit.
DEVI void conv_compute_store(unsigned short* Xs, const unsigned short* __restrict__ Wbf,
                             const float* __restrict__ bcv, unsigned short* dstb, int tid)
{
    const int lane = tid & 63, wid = tid >> 6;
    const int wm = wid >> 1, wn = wid & 1;
    const int lr = lane & 15, lg = lane >> 4;

    f32x4 acc[5][4] = {};
#pragma unroll
    for (int kk = 0; kk < 4; ++kk) {
        s16x8 xa[5], wb[4];
#pragma unroll
        for (int at = 0; at < 5; ++at) {
            const int n = wm * 80 + at * 16 + lr;
            const int cqs = ((kk * 8 + lg * 2) ^ (((n >> 2) & 7) << 1)) * 4;
            xa[at] = *reinterpret_cast<const s16x8*>(&Xs[n * 136 + cqs]);
        }
#pragma unroll
        for (int bt = 0; bt < 4; ++bt)
            wb[bt] = *reinterpret_cast<const s16x8*>(
                Wbf + (wn * 64 + bt * 16 + lr) * 128 + kk * 32 + lg * 8);
#pragma unroll
        for (int at = 0; at < 5; ++at)
#pragma unroll
            for (int bt = 0; bt < 4; ++bt)
                acc[at][bt] = __builtin_amdgcn_mfma_f32_16x16x32_bf16(xa[at], wb[bt], acc[at][bt], 0, 0, 0);
    }
    __syncthreads();
#pragma unroll
    for (int bt = 0; bt < 4; ++bt) {
        const int o = wn * 64 + bt * 16 + lr;
        const float bias = bcv[o];
#pragma unroll
        for (int at = 0; at < 5; ++at) {
            const int n0 = wm * 80 + at * 16 + lg * 4;
            ushort4 hv = { f2bf(acc[at][bt][0] + bias), f2bf(acc[at][bt][1] + bias),
                           f2bf(acc[at][bt][2] + bias), f2bf(acc[at][bt][3] + bias) };
            *reinterpret_cast<ushort4*>(&Xs[o * 168 + n0]) = hv;
        }
    }
    __syncthreads();
#pragma unroll
    for (int j = 0; j < 10; ++j) {
        const int item = tid + j * 256;      // 2560 = 128 o x 20 segs
        const int o = item / 20, s2 = item % 20;
        *reinterpret_cast<s16x8*>(dstb + (size_t)o * 129600 + s2 * 8) =
            *reinterpret_cast<const s16x8*>(&Xs[o * 168 + s2 * 8]);
    }
    __syncthreads(); // Xs free
}

// ---------------------------------------------------------------------------
// Kernel 1: 1x1 conv GEMM. rb-PAIR per block (grid 1620): two sequential R7
// tile passes -> each block owns 640 B (128-aligned) per XR row -> no
// cross-XCD partial-line sharing on the store. No prefetch (R8 lesson).
// XR: bf16 [bo=512][81][1600]
__global__ __launch_bounds__(256, 3) void k_conv(
    const float* __restrict__ x, const unsigned short* __restrict__ Wbf,
    const float* __restrict__ bcv, unsigned short* __restrict__ XR)
{
    __shared__ __align__(16) unsigned short Xs[160 * 136]; // 43.5 KB
    const int tid = threadIdx.x;
    int bid = blockIdx.x;
    const int rb2 = bid % 5; bid /= 5;
    const int cw = bid % 9;  bid /= 9;
    const int ch = bid % 9;  const int b = bid / 9;
    const int w0 = cw * 40;
    const int kfeat = ch * 9 + cw;
    const int rb0 = rb2 * 2;
    const int H0 = ch * 40 + rb0 * 4;

    const float* xb = x + (size_t)b * 128 * 129600;
    unsigned short* dst0 = XR + (size_t)(b * 128) * 129600 + (size_t)kfeat * 1600;

    float4 va[5][4];
#pragma unroll
    for (int h = 0; h < 2; ++h) {
        conv_issue(xb, H0 + 4 * h, w0, tid, va);
        conv_stage(va, Xs, tid);
        __syncthreads();
        conv_compute_store(Xs, Wbf, bcv, dst0 + (rb0 + h) * 160, tid);
    }
}

// ---------------------------------------------------------------------------
// Kernel 2: partial Gram per (half,bo): G2 = R R^T over 800 tokens (96-pad),
// row 81 = ones so col 81 = partial s.  Grid 1024.
__global__ __launch_bounds__(256) void k_gram(
    const unsigned short* __restrict__ XR, float* __restrict__ G2)
{
    __shared__ __align__(16) unsigned short Rs[96 * 168];
    const int tid = threadIdx.x;
    const int half = blockIdx.x & 1, bo = blockIdx.x >> 1;
    for (int i = 81 * 168 + tid; i < 96 * 168; i += 256)
        Rs[i] = (i < 82 * 168) ? (unsigned short)0x3F80 : (unsigned short)0;
    const unsigned short* Rg = XR + (size_t)bo * 129600;
    const int lane = tid & 63, wid = tid >> 6;
    const int wm = wid >> 1, wn = wid & 1;
    const int lr = lane & 15, lg = lane >> 4;
    f32x4 acc[3][3] = {};
    for (int it = 0; it < 5; ++it) {
        const int t0 = half * 800 + it * 160;
        __syncthreads();
        for (int i = tid; i < 81 * 20; i += 256) {
            const int r = i / 20, g = i % 20;
            *reinterpret_cast<s16x8*>(&Rs[r * 168 + g * 8]) =
                *reinterpret_cast<const s16x8*>(Rg + (size_t)r * 1600 + t0 + g * 8);
        }
        __syncthreads();
#pragma unroll
        for (int kk = 0; kk < 5; ++kk) {
            const int koff = kk * 32 + lg * 8;
            s16x8 af[3], bfr[3];
#pragma unroll
            for (int mt = 0; mt < 3; ++mt)
                af[mt] = *reinterpret_cast<const s16x8*>(&Rs[(wm * 48 + mt * 16 + lr) * 168 + koff]);
#pragma unroll
            for (int nt = 0; nt < 3; ++nt)
                bfr[nt] = *reinterpret_cast<const s16x8*>(&Rs[(wn * 48 + nt * 16 + lr) * 168 + koff]);
#pragma unroll
            for (int mt = 0; mt < 3; ++mt)
#pragma unroll
                for (int nt = 0; nt < 3; ++nt)
                    acc[mt][nt] = __builtin_amdgcn_mfma_f32_16x16x32_bf16(af[mt], bfr[nt], acc[mt][nt], 0, 0, 0);
        }
    }
    float* Gb = G2 + (size_t)(half * 512 + bo) * 9216;
#pragma unroll
    for (int mt = 0; mt < 3; ++mt)
#pragma unroll
        for (int nt = 0; nt < 3; ++nt)
#pragma unroll
            for (int rg = 0; rg < 4; ++rg) {
                const int row = wm * 48 + mt * 16 + lg * 4 + rg;
                const int col = wn * 48 + nt * 16 + lr;
                Gb[row * 96 + col] = acc[mt][nt][rg];
            }
}

// ---------------------------------------------------------------------------
// Kernel 3: per bo: OUT = EA * Ghat * WCA^T / 9. NT[q][k] = OUT[k][q].
__global__ __launch_bounds__(256) void k_small(
    const float* __restrict__ G2, const float* __restrict__ EAT,
    const float* __restrict__ WCAT, unsigned short* __restrict__ NT)
{
    __shared__ float Gs[96 * 98];
    __shared__ float Us[96 * 98];
    const int tid = threadIdx.x;
    const int bo = blockIdx.x;
    const int ty = tid >> 4, tx = tid & 15;
    const int r0 = ty * 6, q0 = tx * 6;

    const float* Gg0 = G2 + (size_t)bo * 9216;
    const float* Gg1 = G2 + (size_t)(512 + bo) * 9216;
    for (int i = tid; i < 96 * 96; i += 256) {
        const int r = i / 96, c = i % 96;
        Gs[r * 98 + c] = Gg0[i] + Gg1[i];
    }
    __syncthreads();

    {
        float acc[6][6] = {};
        for (int l = 0; l <= 81; ++l) {
            float gv[6], wv[6];
#pragma unroll
            for (int a = 0; a < 6; ++a) gv[a] = Gs[l * 98 + r0 + a];
#pragma unroll
            for (int b2 = 0; b2 < 6; ++b2) wv[b2] = WCAT[l * 96 + q0 + b2];
#pragma unroll
            for (int a = 0; a < 6; ++a)
#pragma unroll
                for (int b2 = 0; b2 < 6; ++b2)
                    acc[a][b2] += gv[a] * wv[b2];
        }
#pragma unroll
        for (int a = 0; a < 6; ++a)
#pragma unroll
            for (int b2 = 0; b2 < 6; ++b2)
                Us[(r0 + a) * 98 + q0 + b2] = acc[a][b2];
    }
    __syncthreads();

    float acc[6][6] = {};
    for (int j = 0; j <= 81; ++j) {
        float ev[6], uv[6];
#pragma unroll
        for (int a = 0; a < 6; ++a) ev[a] = EAT[j * 96 + r0 + a];
#pragma unroll
        for (int b2 = 0; b2 < 6; ++b2) uv[b2] = Us[j * 98 + q0 + b2];
#pragma unroll
        for (int a = 0; a < 6; ++a)
#pragma unroll
            for (int b2 = 0; b2 < 6; ++b2)
                acc[a][b2] += ev[a] * uv[b2];
    }
    unsigned short* NTb = NT + (size_t)bo * 9216;
#pragma unroll
    for (int b2 = 0; b2 < 6; ++b2)
#pragma unroll
        for (int a = 0; a < 6; ++a)
            NTb[(q0 + b2) * 96 + (r0 + a)] = f2bf(acc[a][b2] * (1.f / 9.f));
}

// ---------------------------------------------------------------------------
// Kernel 4: y[t][q] = sum_k x~[t][k] N[k][q] + m[q]. Exact R7 structure
// (grid 2560): col8-XOR swizzled [t][128] LDS, register-transpose staging,
// NT frags hoisted, f32x4 stores.
__global__ __launch_bounds__(256) void k_apply(
    const unsigned short* __restrict__ XR, const unsigned short* __restrict__ NT,
    float* __restrict__ out)
{
    __shared__ __align__(16) unsigned short Xs[160 * 128]; // 40 KB
    const int tid = threadIdx.x;
    const int fifth = blockIdx.x % 5, bo = blockIdx.x / 5;
    // init zeros for logical cols 84..95 (col8 = 10 upper half, col8 = 11)
    for (int i = tid; i < 320; i += 256) {
        const int t = i >> 1, h = i & 1;
        const int s = (t >> 3) & 7;
        const ushort4 z = { 0, 0, 0, 0 };
        if (h == 0) {
            *reinterpret_cast<ushort4*>(&Xs[t * 128 + ((10 ^ s) << 3) + 4]) = z;
        } else {
            *reinterpret_cast<ushort4*>(&Xs[t * 128 + ((11 ^ s) << 3)]) = z;
            *reinterpret_cast<ushort4*>(&Xs[t * 128 + ((11 ^ s) << 3) + 4]) = z;
        }
    }
    const int lane = tid & 63, wid = tid >> 6;
    const int wm = wid >> 1, wn = wid & 1;  // wm: t-half (80), wn: q-half (48)
    const int lr = lane & 15, lg = lane >> 4;

    const unsigned short* NTb = NT + (size_t)bo * 9216;
    s16x8 nb[3][3];
#pragma unroll
    for (int qt = 0; qt < 3; ++qt)
#pragma unroll
        for (int kk = 0; kk < 3; ++kk)
            nb[qt][kk] = *reinterpret_cast<const s16x8*>(
                NTb + (wn * 48 + qt * 16 + lr) * 96 + kk * 32 + lg * 8);

    const unsigned short* Rg = XR + (size_t)bo * 129600;
    float* ob = out + (size_t)bo * 129600;

    for (int it = 0; it < 2; ++it) {
        const int t0 = fifth * 320 + it * 160;
        __syncthreads();
        for (int i = tid; i < 420; i += 256) {
            const int kq = i / 20, g = i % 20;
            if (kq < 20) {
                const unsigned short* src = Rg + (size_t)(4 * kq) * 1600 + t0 + g * 8;
                const s16x8 v0 = *reinterpret_cast<const s16x8*>(src);
                const s16x8 v1 = *reinterpret_cast<const s16x8*>(src + 1600);
                const s16x8 v2 = *reinterpret_cast<const s16x8*>(src + 3200);
                const s16x8 v3 = *reinterpret_cast<const s16x8*>(src + 4800);
                const int colb = (((kq >> 1) ^ (g & 7)) << 3) + ((kq & 1) << 2);
#pragma unroll
                for (int e = 0; e < 8; ++e) {
                    const int t = g * 8 + e;
                    ushort4 wv = { (unsigned short)v0[e], (unsigned short)v1[e],
                                   (unsigned short)v2[e], (unsigned short)v3[e] };
                    *reinterpret_cast<ushort4*>(&Xs[t * 128 + colb]) = wv;
                }
            } else {
                const s16x8 v = *reinterpret_cast<const s16x8*>(
                    Rg + (size_t)80 * 1600 + t0 + g * 8);
                const int colb = (10 ^ (g & 7)) << 3;
#pragma unroll
                for (int e = 0; e < 8; ++e) {
                    const int t = g * 8 + e;
                    ushort4 wv = { (unsigned short)v[e], (unsigned short)0x3F80, 0, 0 };
                    *reinterpret_cast<ushort4*>(&Xs[t * 128 + colb]) = wv;
                }
            }
        }
        __syncthreads();
        f32x4 acc[5][3] = {};
#pragma unroll
        for (int kk = 0; kk < 3; ++kk) {
            s16x8 xa[5];
#pragma unroll
            for (int at = 0; at < 5; ++at) {
                const int t = wm * 80 + at * 16 + lr;
                const int s = (t >> 3) & 7;
                xa[at] = *reinterpret_cast<const s16x8*>(
                    &Xs[t * 128 + (((kk * 4 + lg) ^ s) << 3)]);
            }
#pragma unroll
            for (int at = 0; at < 5; ++at)
#pragma unroll
                for (int qt = 0; qt < 3; ++qt)
                    acc[at][qt] = __builtin_amdgcn_mfma_f32_16x16x32_bf16(xa[at], nb[qt][kk], acc[at][qt], 0, 0, 0);
        }
#pragma unroll
        for (int qt = 0; qt < 3; ++qt) {
            const int q = wn * 48 + qt * 16 + lr;
            if (q < 81) {
                const int chq = q / 9, cwq = q % 9;
                float* oq = ob + (size_t)chq * 40 * 360 + cwq * 40;
#pragma unroll
                for (int at = 0; at < 5; ++at) {
                    const int tt = t0 + wm * 80 + at * 16 + lg * 4;
                    const int hh = tt / 40, ww = tt % 40;
                    *reinterpret_cast<f32x4*>(&oq[hh * 360 + ww]) = acc[at][qt];
                }
            }
        }
    }
}

// ---------------------------------------------------------------------------
extern "C" void kernel_launch(void* const* d_in, const int* in_sizes, int n_in,
                              void* d_out, int out_size, void* d_ws, size_t ws_size,
                              hipStream_t stream)
{
    (void)in_sizes; (void)n_in; (void)out_size; (void)ws_size;
    const float* x   = (const float*)d_in[0];
    const float* Wcv = (const float*)d_in[1];
    const float* bcv = (const float*)d_in[2];
    const float* Wa  = (const float*)d_in[3];
    const float* ba  = (const float*)d_in[4];
    const float* Wb  = (const float*)d_in[5];
    const float* bbv = (const float*)d_in[6];
    const float* Wc  = (const float*)d_in[7];
    const float* bc2 = (const float*)d_in[8];
    float* out = (float*)d_out;

    // ws: XR 132,710,400 | G2 37,748,736 | NT 9,437,184 | Wbf 32,768
    //   | EAT 36,864 | WCAT 36,864
    char* w = (char*)d_ws;
    unsigned short* XR = (unsigned short*)w;
    float* G2 = (float*)(w + 132710400ull);
    unsigned short* NT = (unsigned short*)(w + 170459136ull);
    unsigned short* Wbf = (unsigned short*)(w + 179896320ull);
    float* EAT  = (float*)(w + 179929088ull);
    float* WCAT = (float*)(w + 179965952ull);

    k_prep <<<100,  256, 0, stream>>>(Wcv, Wa, ba, Wb, bbv, Wc, bc2, Wbf, EAT, WCAT);
    k_conv <<<1620, 256, 0, stream>>>(x, Wbf, bcv, XR);
    k_gram <<<1024, 256, 0, stream>>>(XR, G2);
    k_small<<<512,  256, 0, stream>>>(G2, EAT, WCAT, NT);
    k_apply<<<2560, 256, 0, stream>>>(XR, NT, out);
}

// Round 11
// 310.310 us; speedup vs baseline: 1.1715x; 1.0696x over previous
//
#include <hip/hip_runtime.h>
#include <hip/hip_bf16.h>

typedef float f32x4 __attribute__((ext_vector_type(4)));
typedef short s16x8 __attribute__((ext_vector_type(8)));

#define DEVI __device__ __forceinline__

DEVI unsigned short f2bf(float f) {
    return __builtin_bit_cast(unsigned short, __float2bfloat16(f));
}

// Geometry: B=4, C=128, H=W=360, r=9, h=w=40, T=1600 tokens, R2=81 features.
// token t = hh*40+ww, feature k = ch*9+cw, pixel (ch*40+hh, cw*40+ww).
// MFMA mapping (verified R1-R10): D col = lane&15 = B-operand row,
// D row = (lane>>4)*4 + reg = A-operand row; A/B frag: row = lane&15,
// k = (lane>>4)*8 + elem.

// ---------------------------------------------------------------------------
// Kernel 0 (fused prep):
//  blocks 0..63 : Wconv f32 -> bf16
//  blocks 64..99: EAT[j][i] = sum_p WA'[p][i] WB'[p][j]; WCAT[l][q] = Wc[q][l]/bc[q].
__global__ __launch_bounds__(256) void k_prep(
    const float* __restrict__ W, const float* __restrict__ Wa,
    const float* __restrict__ ba, const float* __restrict__ Wb,
    const float* __restrict__ bb, const float* __restrict__ Wc,
    const float* __restrict__ bc, unsigned short* __restrict__ Wbf,
    float* __restrict__ EAT, float* __restrict__ WCAT)
{
    const int tid = threadIdx.x, bid = blockIdx.x;
    if (bid < 64) {
        const int i = bid * 256 + tid;
        Wbf[i] = f2bf(W[i]);
        return;
    }
    const int out = (bid - 64) * 256 + tid; // 0..9215
    const int row = out / 96, col = out % 96;
    float ea = 0.f;
    if (row <= 81 && col <= 81) {
        for (int p = 0; p < 81; ++p) {
            const float wa = (col < 81) ? Wa[p * 81 + col] : ba[p];
            const float wb = (row < 81) ? Wb[p * 81 + row] : bb[p];
            ea += wa * wb;
        }
    }
    EAT[out] = ea;
    float wc = 0.f;
    if (col < 81) {
        if (row < 81) wc = Wc[col * 81 + row];
        else if (row == 81) wc = bc[col];
    }
    WCAT[out] = wc;
}

// ---------------------------------------------------------------------------
// Kernel 1: 1x1 conv GEMM, grid 3240 (R7 structure). LDS = [160 n][128 c]
// with octet XOR p = c8 ^ (n&7): 40,960 B exactly -> 4 blocks/CU.
// Stage item map cq=(i>>2)&31, nq=((i>>7)<<2)|(i&3): wave writes span all
// octets (conflict-free b64), global loads keep 64B streams.
// Bounce [o][160] with seg rotate (s+o%20)%20. XR: bf16 [bo=512][81][1600]
__global__ __launch_bounds__(256, 3) void k_conv(
    const float* __restrict__ x, const unsigned short* __restrict__ Wbf,
    const float* __restrict__ bcv, unsigned short* __restrict__ XR)
{
    __shared__ __align__(16) unsigned short Xs[160 * 128]; // 40,960 B
    const int tid = threadIdx.x;
    int bid = blockIdx.x;
    const int rb = bid % 10; bid /= 10;
    const int cw = bid % 9;  bid /= 9;
    const int ch = bid % 9;  const int b = bid / 9;
    const int H0 = ch * 40 + rb * 4, w0 = cw * 40;
    const int kfeat = ch * 9 + cw;
    const int t0 = rb * 160;

    // Load batch: 20 float4/thread; item = (cq: 4 channels, nq: 4-pixel quad).
    const float* xb = x + (size_t)b * 128 * 129600;
    float4 va[5][4];
#pragma unroll
    for (int ii = 0; ii < 5; ++ii) {
        const int i = tid + ii * 256;
        const int cq = (i >> 2) & 31;
        const int nq = ((i >> 7) << 2) | (i & 3);
        const int hh = nq / 10, sub = nq % 10;
        const float* p = xb + (size_t)(cq * 4) * 129600 + (size_t)(H0 + hh) * 360 + w0 + sub * 4;
        va[ii][0] = *reinterpret_cast<const float4*>(p);
        va[ii][1] = *reinterpret_cast<const float4*>(p + 129600);
        va[ii][2] = *reinterpret_cast<const float4*>(p + 2 * 129600);
        va[ii][3] = *reinterpret_cast<const float4*>(p + 3 * 129600);
    }
    // Stage: 4 ushort4 per item into [n][128] with p = (cq>>1) ^ (n&7).
#pragma unroll
    for (int ii = 0; ii < 5; ++ii) {
        const int i = tid + ii * 256;
        const int cq = (i >> 2) & 31;
        const int nq = ((i >> 7) << 2) | (i & 3);
        const int hh = nq / 10, sub = nq % 10;
        const int n0 = hh * 40 + sub * 4;
        const int cqh = cq >> 1, half4 = (cq & 1) << 2;
        const float4 v0 = va[ii][0], v1 = va[ii][1], v2 = va[ii][2], v3 = va[ii][3];
        ushort4 w0v = { f2bf(v0.x), f2bf(v1.x), f2bf(v2.x), f2bf(v3.x) };
        ushort4 w1v = { f2bf(v0.y), f2bf(v1.y), f2bf(v2.y), f2bf(v3.y) };
        ushort4 w2v = { f2bf(v0.z), f2bf(v1.z), f2bf(v2.z), f2bf(v3.z) };
        ushort4 w3v = { f2bf(v0.w), f2bf(v1.w), f2bf(v2.w), f2bf(v3.w) };
        *reinterpret_cast<ushort4*>(&Xs[(n0 + 0) * 128 + ((cqh ^ ((n0 + 0) & 7)) << 3) + half4]) = w0v;
        *reinterpret_cast<ushort4*>(&Xs[(n0 + 1) * 128 + ((cqh ^ ((n0 + 1) & 7)) << 3) + half4]) = w1v;
        *reinterpret_cast<ushort4*>(&Xs[(n0 + 2) * 128 + ((cqh ^ ((n0 + 2) & 7)) << 3) + half4]) = w2v;
        *reinterpret_cast<ushort4*>(&Xs[(n0 + 3) * 128 + ((cqh ^ ((n0 + 3) & 7)) << 3) + half4]) = w3v;
    }
    __syncthreads();

    const int lane = tid & 63, wid = tid >> 6;
    const int wm = wid >> 1, wn = wid & 1;  // wm: t-half (80), wn: o-half (64)
    const int lr = lane & 15, lg = lane >> 4;

    f32x4 acc[5][4] = {};
#pragma unroll
    for (int kk = 0; kk < 4; ++kk) {
        s16x8 xa[5], wb[4];
#pragma unroll
        for (int at = 0; at < 5; ++at) {
            const int n = wm * 80 + at * 16 + lr;
            const int p8 = (kk * 4 + lg) ^ (n & 7);
            xa[at] = *reinterpret_cast<const s16x8*>(&Xs[n * 128 + (p8 << 3)]);
        }
#pragma unroll
        for (int bt = 0; bt < 4; ++bt)
            wb[bt] = *reinterpret_cast<const s16x8*>(
                Wbf + (wn * 64 + bt * 16 + lr) * 128 + kk * 32 + lg * 8);
#pragma unroll
        for (int at = 0; at < 5; ++at)
#pragma unroll
            for (int bt = 0; bt < 4; ++bt)
                acc[at][bt] = __builtin_amdgcn_mfma_f32_16x16x32_bf16(xa[at], wb[bt], acc[at][bt], 0, 0, 0);
    }
    // Bounce: acc -> [o][160] with segment rotate (s + o%20)%20.
    __syncthreads();
#pragma unroll
    for (int bt = 0; bt < 4; ++bt) {
        const int o = wn * 64 + bt * 16 + lr;
        const int om = o % 20;
        const float bias = bcv[o];
#pragma unroll
        for (int at = 0; at < 5; ++at) {
            const int n0 = wm * 80 + at * 16 + lg * 4;
            int seg = (n0 >> 3) + om; if (seg >= 20) seg -= 20;
            const int h4 = n0 & 4;
            ushort4 hv = { f2bf(acc[at][bt][0] + bias), f2bf(acc[at][bt][1] + bias),
                           f2bf(acc[at][bt][2] + bias), f2bf(acc[at][bt][3] + bias) };
            *reinterpret_cast<ushort4*>(&Xs[o * 160 + seg * 8 + h4]) = hv;
        }
    }
    __syncthreads();
    unsigned short* dstb = XR + (size_t)b * 128 * 129600 + (size_t)kfeat * 1600 + t0;
#pragma unroll
    for (int j = 0; j < 10; ++j) {
        const int item = tid + j * 256;      // 2560 = 128 o x 20 segs
        const int o = item / 20, s2 = item % 20;
        int seg = s2 + o % 20; if (seg >= 20) seg -= 20;
        *reinterpret_cast<s16x8*>(dstb + (size_t)o * 129600 + s2 * 8) =
            *reinterpret_cast<const s16x8*>(&Xs[o * 160 + seg * 8]);
    }
}

// ---------------------------------------------------------------------------
// Kernel 2: partial Gram per (half,bo): G2 = R R^T over 800 tokens (96-pad),
// row 81 = ones so col 81 = partial s.  Grid 1024.
__global__ __launch_bounds__(256) void k_gram(
    const unsigned short* __restrict__ XR, float* __restrict__ G2)
{
    __shared__ __align__(16) unsigned short Rs[96 * 168];
    const int tid = threadIdx.x;
    const int half = blockIdx.x & 1, bo = blockIdx.x >> 1;
    for (int i = 81 * 168 + tid; i < 96 * 168; i += 256)
        Rs[i] = (i < 82 * 168) ? (unsigned short)0x3F80 : (unsigned short)0;
    const unsigned short* Rg = XR + (size_t)bo * 129600;
    const int lane = tid & 63, wid = tid >> 6;
    const int wm = wid >> 1, wn = wid & 1;
    const int lr = lane & 15, lg = lane >> 4;
    f32x4 acc[3][3] = {};
    for (int it = 0; it < 5; ++it) {
        const int t0 = half * 800 + it * 160;
        __syncthreads();
        for (int i = tid; i < 81 * 20; i += 256) {
            const int r = i / 20, g = i % 20;
            *reinterpret_cast<s16x8*>(&Rs[r * 168 + g * 8]) =
                *reinterpret_cast<const s16x8*>(Rg + (size_t)r * 1600 + t0 + g * 8);
        }
        __syncthreads();
#pragma unroll
        for (int kk = 0; kk < 5; ++kk) {
            const int koff = kk * 32 + lg * 8;
            s16x8 af[3], bfr[3];
#pragma unroll
            for (int mt = 0; mt < 3; ++mt)
                af[mt] = *reinterpret_cast<const s16x8*>(&Rs[(wm * 48 + mt * 16 + lr) * 168 + koff]);
#pragma unroll
            for (int nt = 0; nt < 3; ++nt)
                bfr[nt] = *reinterpret_cast<const s16x8*>(&Rs[(wn * 48 + nt * 16 + lr) * 168 + koff]);
#pragma unroll
            for (int mt = 0; mt < 3; ++mt)
#pragma unroll
                for (int nt = 0; nt < 3; ++nt)
                    acc[mt][nt] = __builtin_amdgcn_mfma_f32_16x16x32_bf16(af[mt], bfr[nt], acc[mt][nt], 0, 0, 0);
        }
    }
    float* Gb = G2 + (size_t)(half * 512 + bo) * 9216;
#pragma unroll
    for (int mt = 0; mt < 3; ++mt)
#pragma unroll
        for (int nt = 0; nt < 3; ++nt)
#pragma unroll
            for (int rg = 0; rg < 4; ++rg) {
                const int row = wm * 48 + mt * 16 + lg * 4 + rg;
                const int col = wn * 48 + nt * 16 + lr;
                Gb[row * 96 + col] = acc[mt][nt][rg];
            }
}

// ---------------------------------------------------------------------------
// Kernel 3: per bo: OUT = EA * Ghat * WCA^T / 9. NT[q][k] = OUT[k][q].
__global__ __launch_bounds__(256) void k_small(
    const float* __restrict__ G2, const float* __restrict__ EAT,
    const float* __restrict__ WCAT, unsigned short* __restrict__ NT)
{
    __shared__ float Gs[96 * 98];
    __shared__ float Us[96 * 98];
    const int tid = threadIdx.x;
    const int bo = blockIdx.x;
    const int ty = tid >> 4, tx = tid & 15;
    const int r0 = ty * 6, q0 = tx * 6;

    const float* Gg0 = G2 + (size_t)bo * 9216;
    const float* Gg1 = G2 + (size_t)(512 + bo) * 9216;
    for (int i = tid; i < 96 * 96; i += 256) {
        const int r = i / 96, c = i % 96;
        Gs[r * 98 + c] = Gg0[i] + Gg1[i];
    }
    __syncthreads();

    {
        float acc[6][6] = {};
        for (int l = 0; l <= 81; ++l) {
            float gv[6], wv[6];
#pragma unroll
            for (int a = 0; a < 6; ++a) gv[a] = Gs[l * 98 + r0 + a];
#pragma unroll
            for (int b2 = 0; b2 < 6; ++b2) wv[b2] = WCAT[l * 96 + q0 + b2];
#pragma unroll
            for (int a = 0; a < 6; ++a)
#pragma unroll
                for (int b2 = 0; b2 < 6; ++b2)
                    acc[a][b2] += gv[a] * wv[b2];
        }
#pragma unroll
        for (int a = 0; a < 6; ++a)
#pragma unroll
            for (int b2 = 0; b2 < 6; ++b2)
                Us[(r0 + a) * 98 + q0 + b2] = acc[a][b2];
    }
    __syncthreads();

    float acc[6][6] = {};
    for (int j = 0; j <= 81; ++j) {
        float ev[6], uv[6];
#pragma unroll
        for (int a = 0; a < 6; ++a) ev[a] = EAT[j * 96 + r0 + a];
#pragma unroll
        for (int b2 = 0; b2 < 6; ++b2) uv[b2] = Us[j * 98 + q0 + b2];
#pragma unroll
        for (int a = 0; a < 6; ++a)
#pragma unroll
            for (int b2 = 0; b2 < 6; ++b2)
                acc[a][b2] += ev[a] * uv[b2];
    }
    unsigned short* NTb = NT + (size_t)bo * 9216;
#pragma unroll
    for (int b2 = 0; b2 < 6; ++b2)
#pragma unroll
        for (int a = 0; a < 6; ++a)
            NTb[(q0 + b2) * 96 + (r0 + a)] = f2bf(acc[a][b2] * (1.f / 9.f));
}

// ---------------------------------------------------------------------------
// Kernel 4: y[t][q] = sum_k x~[t][k] N[k][q] + m[q]. Exact R7 structure
// (grid 2560): col8-XOR swizzled [t][128] LDS, register-transpose staging,
// NT frags hoisted, f32x4 stores.
__global__ __launch_bounds__(256) void k_apply(
    const unsigned short* __restrict__ XR, const unsigned short* __restrict__ NT,
    float* __restrict__ out)
{
    __shared__ __align__(16) unsigned short Xs[160 * 128]; // 40 KB
    const int tid = threadIdx.x;
    const int fifth = blockIdx.x % 5, bo = blockIdx.x / 5;
    // init zeros for logical cols 84..95 (col8 = 10 upper half, col8 = 11)
    for (int i = tid; i < 320; i += 256) {
        const int t = i >> 1, h = i & 1;
        const int s = (t >> 3) & 7;
        const ushort4 z = { 0, 0, 0, 0 };
        if (h == 0) {
            *reinterpret_cast<ushort4*>(&Xs[t * 128 + ((10 ^ s) << 3) + 4]) = z;
        } else {
            *reinterpret_cast<ushort4*>(&Xs[t * 128 + ((11 ^ s) << 3)]) = z;
            *reinterpret_cast<ushort4*>(&Xs[t * 128 + ((11 ^ s) << 3) + 4]) = z;
        }
    }
    const int lane = tid & 63, wid = tid >> 6;
    const int wm = wid >> 1, wn = wid & 1;  // wm: t-half (80), wn: q-half (48)
    const int lr = lane & 15, lg = lane >> 4;

    const unsigned short* NTb = NT + (size_t)bo * 9216;
    s16x8 nb[3][3];
#pragma unroll
    for (int qt = 0; qt < 3; ++qt)
#pragma unroll
        for (int kk = 0; kk < 3; ++kk)
            nb[qt][kk] = *reinterpret_cast<const s16x8*>(
                NTb + (wn * 48 + qt * 16 + lr) * 96 + kk * 32 + lg * 8);

    const unsigned short* Rg = XR + (size_t)bo * 129600;
    float* ob = out + (size_t)bo * 129600;

    for (int it = 0; it < 2; ++it) {
        const int t0 = fifth * 320 + it * 160;
        __syncthreads();
        for (int i = tid; i < 420; i += 256) {
            const int kq = i / 20, g = i % 20;
            if (kq < 20) {
                const unsigned short* src = Rg + (size_t)(4 * kq) * 1600 + t0 + g * 8;
                const s16x8 v0 = *reinterpret_cast<const s16x8*>(src);
                const s16x8 v1 = *reinterpret_cast<const s16x8*>(src + 1600);
                const s16x8 v2 = *reinterpret_cast<const s16x8*>(src + 3200);
                const s16x8 v3 = *reinterpret_cast<const s16x8*>(src + 4800);
                const int colb = (((kq >> 1) ^ (g & 7)) << 3) + ((kq & 1) << 2);
#pragma unroll
                for (int e = 0; e < 8; ++e) {
                    const int t = g * 8 + e;
                    ushort4 wv = { (unsigned short)v0[e], (unsigned short)v1[e],
                                   (unsigned short)v2[e], (unsigned short)v3[e] };
                    *reinterpret_cast<ushort4*>(&Xs[t * 128 + colb]) = wv;
                }
            } else {
                const s16x8 v = *reinterpret_cast<const s16x8*>(
                    Rg + (size_t)80 * 1600 + t0 + g * 8);
                const int colb = (10 ^ (g & 7)) << 3;
#pragma unroll
                for (int e = 0; e < 8; ++e) {
                    const int t = g * 8 + e;
                    ushort4 wv = { (unsigned short)v[e], (unsigned short)0x3F80, 0, 0 };
                    *reinterpret_cast<ushort4*>(&Xs[t * 128 + colb]) = wv;
                }
            }
        }
        __syncthreads();
        f32x4 acc[5][3] = {};
#pragma unroll
        for (int kk = 0; kk < 3; ++kk) {
            s16x8 xa[5];
#pragma unroll
            for (int at = 0; at < 5; ++at) {
                const int t = wm * 80 + at * 16 + lr;
                const int s = (t >> 3) & 7;
                xa[at] = *reinterpret_cast<const s16x8*>(
                    &Xs[t * 128 + (((kk * 4 + lg) ^ s) << 3)]);
            }
#pragma unroll
            for (int at = 0; at < 5; ++at)
#pragma unroll
                for (int qt = 0; qt < 3; ++qt)
                    acc[at][qt] = __builtin_amdgcn_mfma_f32_16x16x32_bf16(xa[at], nb[qt][kk], acc[at][qt], 0, 0, 0);
        }
#pragma unroll
        for (int qt = 0; qt < 3; ++qt) {
            const int q = wn * 48 + qt * 16 + lr;
            if (q < 81) {
                const int chq = q / 9, cwq = q % 9;
                float* oq = ob + (size_t)chq * 40 * 360 + cwq * 40;
#pragma unroll
                for (int at = 0; at < 5; ++at) {
                    const int tt = t0 + wm * 80 + at * 16 + lg * 4;
                    const int hh = tt / 40, ww = tt % 40;
                    *reinterpret_cast<f32x4*>(&oq[hh * 360 + ww]) = acc[at][qt];
                }
            }
        }
    }
}

// ---------------------------------------------------------------------------
extern "C" void kernel_launch(void* const* d_in, const int* in_sizes, int n_in,
                              void* d_out, int out_size, void* d_ws, size_t ws_size,
                              hipStream_t stream)
{
    (void)in_sizes; (void)n_in; (void)out_size; (void)ws_size;
    const float* x   = (const float*)d_in[0];
    const float* Wcv = (const float*)d_in[1];
    const float* bcv = (const float*)d_in[2];
    const float* Wa  = (const float*)d_in[3];
    const float* ba  = (const float*)d_in[4];
    const float* Wb  = (const float*)d_in[5];
    const float* bbv = (const float*)d_in[6];
    const float* Wc  = (const float*)d_in[7];
    const float* bc2 = (const float*)d_in[8];
    float* out = (float*)d_out;

    // ws: XR 132,710,400 | G2 37,748,736 | NT 9,437,184 | Wbf 32,768
    //   | EAT 36,864 | WCAT 36,864
    char* w = (char*)d_ws;
    unsigned short* XR = (unsigned short*)w;
    float* G2 = (float*)(w + 132710400ull);
    unsigned short* NT = (unsigned short*)(w + 170459136ull);
    unsigned short* Wbf = (unsigned short*)(w + 179896320ull);
    float* EAT  = (float*)(w + 179929088ull);
    float* WCAT = (float*)(w + 179965952ull);

    k_prep <<<100,  256, 0, stream>>>(Wcv, Wa, ba, Wb, bbv, Wc, bc2, Wbf, EAT, WCAT);
    k_conv <<<3240, 256, 0, stream>>>(x, Wbf, bcv, XR);
    k_gram <<<1024, 256, 0, stream>>>(XR, G2);
    k_small<<<512,  256, 0, stream>>>(G2, EAT, WCAT, NT);
    k_apply<<<2560, 256, 0, stream>>>(XR, NT, out);
}